// Round 1
// baseline (1078.565 us; speedup 1.0000x reference)
//
#include <hip/hip_runtime.h>

#define MAX_T 1000
#define EMBED 1024
#define E4    (EMBED / 4)          // 256 float4 per row
#define ROWS_PER_BLOCK 4           // 4 waves/block, 1 wave per row

// Kernel 1: WT[t*EMBED + e] = W[e*MAX_T + t] + b[e]
// Consecutive threads -> consecutive e -> coalesced 4B writes.
// Reads of W are strided but total only 4 MB (L2/L3 absorbs).
__global__ void build_table_kernel(const float* __restrict__ W,
                                   const float* __restrict__ bias,
                                   float* __restrict__ WT) {
    int idx = blockIdx.x * blockDim.x + threadIdx.x;
    if (idx >= MAX_T * EMBED) return;
    int t = idx >> 10;            // idx / EMBED
    int e = idx & (EMBED - 1);    // idx % EMBED
    WT[idx] = W[e * MAX_T + t] + bias[e];
}

// Kernel 2: one 64-lane wave per output row. Wave-uniform timestep load,
// contiguous float4 row copy from the L2-resident table.
__global__ __launch_bounds__(256) void gather_rows_kernel(
        const int* __restrict__ ts,
        const float4* __restrict__ WT4,
        float4* __restrict__ out4,
        int nrows) {
    int wave = threadIdx.x >> 6;          // 0..3
    int lane = threadIdx.x & 63;
    int row  = blockIdx.x * ROWS_PER_BLOCK + wave;
    if (row >= nrows) return;
    int t = ts[row];                      // wave-uniform -> scalar broadcast
    const float4* src = WT4 + (size_t)t   * E4;
    float4*       dst = out4 + (size_t)row * E4;
#pragma unroll
    for (int j = 0; j < E4 / 64; ++j) {   // 4 iters: lane, lane+64, ...
        dst[j * 64 + lane] = src[j * 64 + lane];
    }
}

// Fallback (no workspace): direct gather, still fully correct.
__global__ __launch_bounds__(256) void direct_kernel(
        const int* __restrict__ ts,
        const float* __restrict__ W,
        const float* __restrict__ bias,
        float* __restrict__ out,
        int nrows) {
    int wave = threadIdx.x >> 6;
    int lane = threadIdx.x & 63;
    int row  = blockIdx.x * ROWS_PER_BLOCK + wave;
    if (row >= nrows) return;
    int t = ts[row];
    float* dst = out + (size_t)row * EMBED;
#pragma unroll
    for (int j = 0; j < EMBED / 64; ++j) {
        int e = j * 64 + lane;
        dst[e] = W[e * MAX_T + t] + bias[e];
    }
}

extern "C" void kernel_launch(void* const* d_in, const int* in_sizes, int n_in,
                              void* d_out, int out_size, void* d_ws, size_t ws_size,
                              hipStream_t stream) {
    const int*   ts   = (const int*)d_in[0];
    const float* W    = (const float*)d_in[1];
    const float* bias = (const float*)d_in[2];
    float*       out  = (float*)d_out;
    const int nrows = in_sizes[0];

    const size_t table_bytes = (size_t)MAX_T * EMBED * sizeof(float);
    if (ws_size >= table_bytes) {
        float* WT = (float*)d_ws;
        int n = MAX_T * EMBED;
        build_table_kernel<<<(n + 255) / 256, 256, 0, stream>>>(W, bias, WT);
        int grid = (nrows + ROWS_PER_BLOCK - 1) / ROWS_PER_BLOCK;
        gather_rows_kernel<<<grid, 256, 0, stream>>>(
            ts, (const float4*)WT, (float4*)out, nrows);
    } else {
        int grid = (nrows + ROWS_PER_BLOCK - 1) / ROWS_PER_BLOCK;
        direct_kernel<<<grid, 256, 0, stream>>>(ts, W, bias, out, nrows);
    }
}